// Round 17
// baseline (127.867 us; speedup 1.0000x reference)
//
#include <hip/hip_runtime.h>
#include <hip/hip_bf16.h>
#include <cfloat>
#include <climits>
#include <cstdint>

#define ALPHA 30.0f
#define KSEL 16          // threshold = sorted[:,16] (17th smallest off-diag)
#define P0 1.368f        // candidate cutoff: E[cnt/row]≈82, P(cnt<17)~1e-13
#define P0SQ (P0 * P0)
#define CAP 224          // per-row candidate capacity (mean 82, +15 sigma)
#define TCAP 1664        // per-tile candidate capacity (256² tile: mean 1310, +9.9 sigma)
#define BIGV 1e30f
#define NMAX 4096

typedef __attribute__((ext_vector_type(4))) float f32x4;
typedef __attribute__((ext_vector_type(8))) int i32x8;
typedef __attribute__((ext_vector_type(4))) int i32x4;

#define LDS_PTR(p) ((__attribute__((address_space(3))) uint32_t*)(p))
#define GLB_PTR(p) ((const __attribute__((address_space(1))) uint32_t*)(p))

__device__ inline float bfval(ushort u) {
    return __builtin_bit_cast(float, (uint32_t)u << 16);
}

// ---------------------------------------------------------------------------
// block reduce helpers (256 threads, 4 waves)
// ---------------------------------------------------------------------------
__device__ inline float blockReduceSumF(float v, float* s) {
    for (int off = 32; off; off >>= 1) v += __shfl_down(v, off);
    int tid = threadIdx.x, wid = tid >> 6;
    if ((tid & 63) == 0) s[wid] = v;
    __syncthreads();
    float r;
    if (tid == 0) { r = s[0] + s[1] + s[2] + s[3]; s[0] = r; }
    __syncthreads();
    r = s[0];
    __syncthreads();
    return r;
}

__device__ inline int blockReduceSumI(int v, int* s) {
    for (int off = 32; off; off >>= 1) v += __shfl_down(v, off);
    int tid = threadIdx.x, wid = tid >> 6;
    if ((tid & 63) == 0) s[wid] = v;
    __syncthreads();
    int r;
    if (tid == 0) { r = s[0] + s[1] + s[2] + s[3]; s[0] = r; }
    __syncthreads();
    r = s[0];
    __syncthreads();
    return r;
}

__device__ inline int blockReduceMaxI(int v, int* s) {
    for (int off = 32; off; off >>= 1) v = max(v, __shfl_down(v, off));
    int tid = threadIdx.x, wid = tid >> 6;
    if ((tid & 63) == 0) s[wid] = v;
    __syncthreads();
    int r;
    if (tid == 0) { r = max(max(s[0], s[1]), max(s[2], s[3])); s[0] = r; }
    __syncthreads();
    r = s[0];
    __syncthreads();
    return r;
}

// ---------------------------------------------------------------------------
// Kernel 1: fused fp32 -> {bf16, fp8 e4m3 (x16)} + row sq-norm; blocks >= N
// do labelinfo. (identical to R14/R16 version — proven)
// ---------------------------------------------------------------------------
__global__ __launch_bounds__(256) void prep_kernel(const float* __restrict__ X,
                                                   ushort* __restrict__ Xbf,
                                                   uint32_t* __restrict__ Xb8,
                                                   float* __restrict__ sq,
                                                   const int* __restrict__ targets,
                                                   int* __restrict__ f1,
                                                   int* __restrict__ f2,
                                                   int* __restrict__ lcnt,
                                                   int D, int N) {
    __shared__ float sw[4];
    __shared__ int s1[4], s2[4], sc[4];
    int tid = threadIdx.x;
    int wid = tid >> 6;

    if (blockIdx.x >= (unsigned)N) {
        int lbl = blockIdx.x - N;
        int a1 = INT_MAX, a2 = INT_MAX, c = 0;
        for (int j = tid; j < N; j += 256) {
            if (targets[j] == lbl) {
                ++c;
                if (j < a1) { a2 = a1; a1 = j; }
                else if (j < a2) a2 = j;
            }
        }
        for (int off = 32; off; off >>= 1) {
            int b1 = __shfl_down(a1, off), b2 = __shfl_down(a2, off), bc = __shfl_down(c, off);
            int m1 = min(a1, b1);
            int m2 = min(max(a1, b1), min(a2, b2));
            a1 = m1; a2 = m2; c += bc;
        }
        if ((tid & 63) == 0) { s1[wid] = a1; s2[wid] = a2; sc[wid] = c; }
        __syncthreads();
        if (tid == 0) {
            int r1 = s1[0], r2 = s2[0], rc = sc[0];
            for (int w = 1; w < 4; ++w) {
                int m1 = min(r1, s1[w]);
                int m2 = min(max(r1, s1[w]), min(r2, s2[w]));
                r1 = m1; r2 = m2; rc += sc[w];
            }
            f1[lbl] = r1; f2[lbl] = r2; lcnt[lbl] = rc;
        }
        return;
    }

    int row = blockIdx.x;
    const float4* xr = reinterpret_cast<const float4*>(X + (size_t)row * D);
    ushort4* xo = reinterpret_cast<ushort4*>(Xbf + (size_t)row * D);
    uint32_t* x8o = Xb8 + (size_t)row * (D / 4);
    float s = 0.f;
    for (int c = tid; c < D / 4; c += 256) {
        float4 v = xr[c];
        s += v.x * v.x + v.y * v.y + v.z * v.z + v.w * v.w;
        ushort4 o;
        uint32_t b;
        b = __builtin_bit_cast(uint32_t, v.x); o.x = (ushort)((b + 0x7FFF + ((b >> 16) & 1)) >> 16);
        b = __builtin_bit_cast(uint32_t, v.y); o.y = (ushort)((b + 0x7FFF + ((b >> 16) & 1)) >> 16);
        b = __builtin_bit_cast(uint32_t, v.z); o.z = (ushort)((b + 0x7FFF + ((b >> 16) & 1)) >> 16);
        b = __builtin_bit_cast(uint32_t, v.w); o.w = (ushort)((b + 0x7FFF + ((b >> 16) & 1)) >> 16);
        xo[c] = o;
        // fp8 e4m3 of 16*x (e4m3 sweet spot); GEMM epilogue divides acc by 256
        int pk = __builtin_amdgcn_cvt_pk_fp8_f32(v.x * 16.f, v.y * 16.f, 0, false);
        pk = __builtin_amdgcn_cvt_pk_fp8_f32(v.z * 16.f, v.w * 16.f, pk, true);
        x8o[c] = (uint32_t)pk;
    }
    for (int off = 32; off; off >>= 1) s += __shfl_down(s, off);
    if ((tid & 63) == 0) sw[wid] = s;
    __syncthreads();
    if (tid == 0) sq[row] = sw[0] + sw[1] + sw[2] + sw[3];
}

// ---------------------------------------------------------------------------
// Kernel 2: 256x256-tile fp8 MFMA GEMM (mfma_scale 16x16x128, neutral scale),
// BK=128 bytes, 8 K-steps. SINGLE-buffered (R16-proven 2-barrier loop):
// LDS 64 KB + 13 KB tlist = 77 KB -> 2 blocks/CU. The co-resident block's
// waves hide each step's vmcnt(0) drain (m114 mechanism) — the ring-2
// double-buffer at 145 KB forced 1 block/CU and bought nothing (R12-R14).
// T2 swizzle byte-geometry identical to R13 (proven). Epilogue: ballot-
// compact to tlist, then fused SINGLE-push scatter (full grid supplies the
// transposed record) — no bin kernel, no tileList (R16-proven pattern).
// ---------------------------------------------------------------------------
#define GBM 256
#define GBK 128
__global__ __launch_bounds__(512) void distgemm_mfma(const uint8_t* __restrict__ Xb8,
                                                     const float* __restrict__ sq,
                                                     float2* __restrict__ cand,
                                                     int* __restrict__ cntArr,
                                                     int* __restrict__ needFB,
                                                     int N, int D) {
    __shared__ uint8_t As[GBM * GBK];   // 32 KB
    __shared__ uint8_t Bs[GBM * GBK];   // 32 KB
    __shared__ float2 tlist[TCAP];      // 13 KB
    __shared__ int s_cnt;

    // XCD swizzle: 256 blocks, 8 XCDs -> 32 consecutive wgids per XCD.
    int wg = blockIdx.x;
    int wgid = (wg & 7) * 32 + (wg >> 3);
    int by = wgid >> 4, bx = wgid & 15;

    int tid = threadIdx.x;
    int lane = tid & 63;
    int wave = tid >> 6;        // 0..7
    int waveM = wave >> 2;      // 0..1  -> 128-row half
    int waveN = wave & 3;       // 0..3  -> 64-col quarter

    int rowBase = by * GBM;
    int colBase = bx * GBM;

    if (tid == 0) s_cnt = 0;

    f32x4 acc[8][4];
#pragma unroll
    for (int m = 0; m < 8; ++m)
#pragma unroll
        for (int n2 = 0; n2 < 4; ++n2) {
            f32x4 z = {0.f, 0.f, 0.f, 0.f};
            acc[m][n2] = z;
        }

    // staging: per K-tile 32KB A + 32KB B; 8 loads/wave (4 rounds x {A,B}).
    // (byte-geometry identical to R13 — proven correct)
    int srow = lane >> 3;                              // 0..7, == row&7
    int sgb = ((lane & 7) << 4) ^ (srow << 4);         // swizzled source byte in row
    auto STAGE = [&](int k0) {
#pragma unroll
        for (int p = 0; p < 4; ++p) {
            int r = p * 64 + wave * 8 + srow;
            const uint8_t* gA = Xb8 + (size_t)(rowBase + r) * D + k0 + sgb;
            const uint8_t* gB = Xb8 + (size_t)(colBase + r) * D + k0 + sgb;
            uint8_t* dA = &As[p * 8192 + wave * 1024];   // + lane*16 implicit
            uint8_t* dB = &Bs[p * 8192 + wave * 1024];
            __builtin_amdgcn_global_load_lds(GLB_PTR(gA), LDS_PTR(dA), 16, 0, 0);
            __builtin_amdgcn_global_load_lds(GLB_PTR(gB), LDS_PTR(dB), 16, 0, 0);
        }
    };

    int l15 = lane & 15;
    int kq32 = (lane >> 4) * 32;          // k-byte quarter base
    int rswz = (l15 & 7) << 4;            // (row&7)<<4, uniform across frags
    int nt = D / GBK;                     // 8

    for (int t = 0; t < nt; ++t) {
        STAGE(t * GBK);
        __syncthreads();   // drains vmcnt(0): tile staged & visible

        i32x8 bF[4];
#pragma unroll
        for (int n2 = 0; n2 < 4; ++n2) {
            int brl = waveN * 64 + n2 * 16 + l15;
            const uint8_t* base = Bs + brl * 128;
            i32x4 lo = *reinterpret_cast<const i32x4*>(base + ((kq32) ^ rswz));
            i32x4 hi = *reinterpret_cast<const i32x4*>(base + ((kq32 + 16) ^ rswz));
            i32x8 f = {lo[0], lo[1], lo[2], lo[3], hi[0], hi[1], hi[2], hi[3]};
            bF[n2] = f;
        }
        __builtin_amdgcn_s_setprio(1);
#pragma unroll
        for (int m = 0; m < 8; ++m) {
            int arl = waveM * 128 + m * 16 + l15;
            const uint8_t* base = As + arl * 128;
            i32x4 lo = *reinterpret_cast<const i32x4*>(base + ((kq32) ^ rswz));
            i32x4 hi = *reinterpret_cast<const i32x4*>(base + ((kq32 + 16) ^ rswz));
            i32x8 aF = {lo[0], lo[1], lo[2], lo[3], hi[0], hi[1], hi[2], hi[3]};
#pragma unroll
            for (int n2 = 0; n2 < 4; ++n2)
                acc[m][n2] = __builtin_amdgcn_mfma_scale_f32_16x16x128_f8f6f4(
                    aF, bF[n2], acc[m][n2], 0, 0, 0, 0x7F, 0, 0x7F);
        }
        __builtin_amdgcn_s_setprio(0);
        __syncthreads();   // all waves done reading before next overwrite
    }

    // epilogue: acc = 256*dot -> v = sqi+sqj-2*dot = sqi+sqj-acc/128
    int cr = (lane >> 4) * 4;
    int cc = lane & 15;
    unsigned long long lmask_lt = (1ull << lane) - 1ull;
#pragma unroll
    for (int m = 0; m < 8; ++m) {
#pragma unroll
        for (int n2 = 0; n2 < 4; ++n2) {
            int gcol = colBase + waveN * 64 + n2 * 16 + cc;
            float sqc = sq[gcol];
#pragma unroll
            for (int r = 0; r < 4; ++r) {
                int grow = rowBase + waveM * 128 + m * 16 + cr + r;
                float v = sq[grow] + sqc - acc[m][n2][r] * 0.0078125f;  // 2/256
                bool pred = (v < P0SQ) && (grow != gcol);
                unsigned long long mask = __ballot(pred);
                if (mask) {
                    int leader = __ffsll((long long)mask) - 1;
                    int tot = __popcll(mask);
                    int base = 0;
                    if (lane == leader) base = atomicAdd(&s_cnt, tot);
                    base = __shfl(base, leader);
                    if (pred) {
                        int idx = base + __popcll(mask & lmask_lt);
                        if (idx < TCAP) {
                            float d = sqrtf(fmaxf(v, 1e-12f));
                            uint32_t pk = ((uint32_t)grow << 12) | (uint32_t)gcol;
                            float2 e; e.x = d; e.y = __builtin_bit_cast(float, pk);
                            tlist[idx] = e;
                        }
                    }
                }
            }
        }
    }
    __syncthreads();

    // fused scatter: single push per record to row-side list; the transposed
    // tile (bx,by) supplies the mirror record (full grid).
    int cnt = min(s_cnt, TCAP);
    for (int e = tid; e < cnt; e += 512) {
        float2 v = tlist[e];
        uint32_t pk = __builtin_bit_cast(uint32_t, v.y);
        int i = (int)(pk >> 12), j = (int)(pk & 4095u);
        int p = atomicAdd(&cntArr[i], 1);
        if (p < CAP) {
            float2 e1; e1.x = v.x; e1.y = __builtin_bit_cast(float, j);
            cand[(size_t)i * CAP + p] = e1;
        }
    }
    if (s_cnt > TCAP && tid < GBM)   // astronomically unlikely; rows lose records
        needFB[rowBase + tid] = 1;
}

// ---------------------------------------------------------------------------
// Kernel 3: per-row finalize from candidate lists. One WAVE per row (4/block).
// (identical to R14/R16 version — proven)
// ---------------------------------------------------------------------------
__global__ __launch_bounds__(256) void rowfinal_kernel(const float2* __restrict__ cand,
                                                       const int* __restrict__ cntArr,
                                                       const int* __restrict__ targets,
                                                       const ushort* __restrict__ Xbf,
                                                       const float* __restrict__ sq,
                                                       const int* __restrict__ f1,
                                                       const int* __restrict__ f2,
                                                       const int* __restrict__ lcnt,
                                                       int* __restrict__ needFB,
                                                       float* __restrict__ rowLoss,
                                                       int N, int D) {
    __shared__ float dbuf[4][CAP];
    int tid = threadIdx.x, lane = tid & 63, w = tid >> 6;
    int row = blockIdx.x * 4 + w;
    int ti = targets[row];
    int lc = lcnt[ti];
    bool validRow = (lc >= 2) && (lc < N);
    int cnt = cntArr[row];
    bool fb = (cnt < KSEL + 1) || (cnt > CAP);
    int lim = fb ? 0 : cnt;

    float ed[4]; int ej[4];
#pragma unroll
    for (int s = 0; s < 4; ++s) {
        int idx = lane + s * 64;
        bool in = (!fb) && (idx < cnt);
        if (in) {
            float2 e = cand[(size_t)row * CAP + idx];
            ed[s] = e.x; ej[s] = __builtin_bit_cast(int, e.y);
            dbuf[w][idx] = e.x;
        } else { ed[s] = BIGV; ej[s] = -1; }
    }
    __syncthreads();

    // exact rank: thr = value at rank KSEL (0-based) among candidates
    int rlo[4] = {0, 0, 0, 0}, req[4] = {0, 0, 0, 0};
    for (int q = 0; q < lim; ++q) {
        float u = dbuf[w][q];
#pragma unroll
        for (int s = 0; s < 4; ++s) {
            rlo[s] += (u < ed[s]);
            req[s] += (u == ed[s]);
        }
    }
    float thrc = BIGV;
#pragma unroll
    for (int s = 0; s < 4; ++s)
        if (ej[s] >= 0 && rlo[s] <= KSEL && KSEL < rlo[s] + req[s]) thrc = fminf(thrc, ed[s]);
    for (int off = 32; off; off >>= 1) thrc = fminf(thrc, __shfl_down(thrc, off));
    float thr = __shfl(thrc, 0);

    // masked sums over candidates (below-thr set fully contained in list)
    float posS = 0.f, negS = 0.f;
    int apb = 0;
#pragma unroll
    for (int s = 0; s < 4; ++s) {
        if (ej[s] >= 0 && ed[s] < thr) {
            bool same = (targets[ej[s]] == ti);
            float e = expf(ALPHA * (1.0f - ed[s]));
            if (same) { posS += e; apb = 1; }
            else negS += e;
        }
    }
    for (int off = 32; off; off >>= 1) {
        posS += __shfl_down(posS, off);
        negS += __shfl_down(negS, off);
        apb = max(apb, __shfl_down(apb, off));
    }

    // first-positive fallback distance (bf16 dot, fp32 accum)
    int fp = 0;
    float dot = 0.f;
    if (validRow) {
        fp = (row == f1[ti]) ? f2[ti] : f1[ti];
        const ushort* xr = Xbf + (size_t)row * D;
        const ushort* xf = Xbf + (size_t)fp * D;
        for (int c = lane; c < D / 4; c += 64) {
            ushort4 a = *reinterpret_cast<const ushort4*>(xr + (size_t)c * 4);
            ushort4 b = *reinterpret_cast<const ushort4*>(xf + (size_t)c * 4);
            dot += bfval(a.x) * bfval(b.x) + bfval(a.y) * bfval(b.y)
                 + bfval(a.z) * bfval(b.z) + bfval(a.w) * bfval(b.w);
        }
    }
    for (int off = 32; off; off >>= 1) dot += __shfl_down(dot, off);

    if (lane == 0) {
        if (fb) {
            needFB[row] = 1;
        } else if (!validRow) {
            rowLoss[row] = BIGV;
        } else {
            float fbD = sqrtf(fmaxf(sq[row] + sq[fp] - 2.0f * dot, 1e-12f));
            float posLogit = apb ? posS : expf(ALPHA * (1.0f - fbD));
            rowLoss[row] = -logf(posLogit / (posLogit + negS));
        }
    }
}

// ---------------------------------------------------------------------------
// Kernel 4: exact fallback (full-row recompute, bf16). Expected zero work.
// (identical to R14/R16 version — proven)
// ---------------------------------------------------------------------------
__global__ __launch_bounds__(256) void fallback_kernel(const ushort* __restrict__ Xbf,
                                                       const float* __restrict__ sq,
                                                       const int* __restrict__ targets,
                                                       const int* __restrict__ needFB,
                                                       const int* __restrict__ f1,
                                                       const int* __restrict__ f2,
                                                       const int* __restrict__ lcnt,
                                                       float* __restrict__ rowLoss,
                                                       int N, int D) {
    int row = blockIdx.x;
    if (!needFB[row]) return;

    __shared__ float xrow[1024];
    __shared__ float rowD[NMAX];
    __shared__ float sF[4];
    __shared__ int sI[4];
    int tid = threadIdx.x;

    for (int k = tid; k < D; k += 256) xrow[k] = bfval(Xbf[(size_t)row * D + k]);
    __syncthreads();

    for (int j = tid; j < N; j += 256) {
        float dot = 0.f;
        const ushort* xj = Xbf + (size_t)j * D;
        for (int k = 0; k < D; ++k) dot += xrow[k] * bfval(xj[k]);
        rowD[j] = (j == row) ? BIGV
                             : sqrtf(fmaxf(sq[row] + sq[j] - 2.0f * dot, 1e-12f));
    }
    __syncthreads();

    uint32_t lo = 0, hi = 0x40800000u;
    while (lo < hi) {
        uint32_t mid = (lo + hi) >> 1;
        float mv = __builtin_bit_cast(float, mid);
        int c = 0;
        for (int j = tid; j < N; j += 256) c += (rowD[j] <= mv);
        c = blockReduceSumI(c, sI);
        if (c >= KSEL + 1) hi = mid; else lo = mid + 1;
    }
    float thr = __builtin_bit_cast(float, hi);

    int ti = targets[row];
    int lc = lcnt[ti];
    bool validRow = (lc >= 2) && (lc < N);

    float posS = 0.f, negS = 0.f;
    int apb = 0;
    for (int j = tid; j < N; j += 256) {
        if (j == row) continue;
        float d = rowD[j];
        bool same = (targets[j] == ti);
        if (d < thr) {
            float e = expf(ALPHA * (1.0f - d));
            if (same) { posS += e; apb = 1; }
            else negS += e;
        }
    }
    posS = blockReduceSumF(posS, sF);
    negS = blockReduceSumF(negS, sF);
    apb = blockReduceMaxI(apb, sI);

    if (tid == 0) {
        if (!validRow) { rowLoss[row] = BIGV; return; }
        int fp = (row == f1[ti]) ? f2[ti] : f1[ti];
        float posLogit = apb ? posS : expf(ALPHA * (1.0f - rowD[fp]));
        rowLoss[row] = -logf(posLogit / (posLogit + negS));
    }
}

// ---------------------------------------------------------------------------
// Kernel 5: single-block reduction over rowLoss -> out[4]
// ---------------------------------------------------------------------------
__global__ __launch_bounds__(256) void reduce_kernel(const float* __restrict__ rowLoss,
                                                     float* __restrict__ out, int N) {
    __shared__ float sF[4];
    __shared__ int sI[4];
    int tid = threadIdx.x;
    float sumL = 0.f;
    int nValid = 0, nAcc = 0;
    for (int j = tid; j < N; j += 256) {
        float L = rowLoss[j];
        if (L != BIGV) {
            sumL += L;
            ++nValid;
            if (L < 0.6f) ++nAcc;
        }
    }
    sumL = blockReduceSumF(sumL, sF);
    nValid = blockReduceSumI(nValid, sI);
    nAcc = blockReduceSumI(nAcc, sI);
    if (tid == 0) {
        out[0] = (nValid > 0) ? sumL / (float)nValid : 0.f;
        out[1] = (float)nAcc / (float)N;
        out[2] = 0.f;
        out[3] = 0.f;
    }
}

// ---------------------------------------------------------------------------
extern "C" void kernel_launch(void* const* d_in, const int* in_sizes, int n_in,
                              void* d_out, int out_size, void* d_ws, size_t ws_size,
                              hipStream_t stream) {
    const float* X = (const float*)d_in[0];
    const int* targets = (const int*)d_in[1];
    float* out = (float*)d_out;

    int N = in_sizes[1];             // 4096
    int D = in_sizes[0] / N;         // 1024
    int tiles = N / GBM;             // 16
    int nTiles = tiles * tiles;      // 256

    // 8B-aligned float2 array first
    float2* cand     = (float2*)d_ws;                          // N*CAP f2 (7.3 MB)
    float*  sq       = (float*)(cand + (size_t)N * CAP);
    float*  rowLoss  = sq + N;
    int*    cntArr   = (int*)(rowLoss + N);
    int*    needFB   = cntArr + N;
    int*    f1       = needFB + N;
    int*    f2       = f1 + 64;
    int*    lcnt     = f2 + 64;
    ushort* Xbf      = (ushort*)(lcnt + 64 + 64);              // N*D bf16 (8 MB)
    uint32_t* Xb8    = (uint32_t*)(Xbf + (size_t)N * D);       // N*D fp8  (4 MB)

    hipMemsetAsync(cntArr, 0, N * sizeof(int), stream);
    hipMemsetAsync(needFB, 0, N * sizeof(int), stream);

    prep_kernel<<<N + 64, 256, 0, stream>>>(X, Xbf, Xb8, sq, targets,
                                            f1, f2, lcnt, D, N);

    distgemm_mfma<<<nTiles, 512, 0, stream>>>((const uint8_t*)Xb8, sq, cand,
                                              cntArr, needFB, N, D);

    rowfinal_kernel<<<N / 4, 256, 0, stream>>>(cand, cntArr, targets, Xbf, sq,
                                               f1, f2, lcnt, needFB, rowLoss, N, D);

    fallback_kernel<<<N, 256, 0, stream>>>(Xbf, sq, targets, needFB,
                                           f1, f2, lcnt, rowLoss, N, D);

    reduce_kernel<<<1, 256, 0, stream>>>(rowLoss, out, N);
}

// Round 18
// 114.234 us; speedup vs baseline: 1.1193x; 1.1193x over previous
//
#include <hip/hip_runtime.h>
#include <hip/hip_bf16.h>
#include <cfloat>
#include <climits>
#include <cstdint>

#define ALPHA 30.0f
#define KSEL 16          // threshold = sorted[:,16] (17th smallest off-diag)
#define P0 1.368f        // candidate cutoff: E[cnt/row]≈82, P(cnt<17)~1e-13
#define P0SQ (P0 * P0)
#define CAP 224          // per-row candidate capacity (mean 82, +15 sigma)
#define TCAP 1664        // per-tile candidate capacity (256² tile: mean 1310, +9.9 sigma)
#define BIGV 1e30f
#define NMAX 4096

typedef __attribute__((ext_vector_type(4))) float f32x4;
typedef __attribute__((ext_vector_type(8))) int i32x8;
typedef __attribute__((ext_vector_type(4))) int i32x4;

#define LDS_PTR(p) ((__attribute__((address_space(3))) uint32_t*)(p))
#define GLB_PTR(p) ((const __attribute__((address_space(1))) uint32_t*)(p))

__device__ inline float bfval(ushort u) {
    return __builtin_bit_cast(float, (uint32_t)u << 16);
}

// ---------------------------------------------------------------------------
// block reduce helpers (256 threads, 4 waves)
// ---------------------------------------------------------------------------
__device__ inline float blockReduceSumF(float v, float* s) {
    for (int off = 32; off; off >>= 1) v += __shfl_down(v, off);
    int tid = threadIdx.x, wid = tid >> 6;
    if ((tid & 63) == 0) s[wid] = v;
    __syncthreads();
    float r;
    if (tid == 0) { r = s[0] + s[1] + s[2] + s[3]; s[0] = r; }
    __syncthreads();
    r = s[0];
    __syncthreads();
    return r;
}

__device__ inline int blockReduceSumI(int v, int* s) {
    for (int off = 32; off; off >>= 1) v += __shfl_down(v, off);
    int tid = threadIdx.x, wid = tid >> 6;
    if ((tid & 63) == 0) s[wid] = v;
    __syncthreads();
    int r;
    if (tid == 0) { r = s[0] + s[1] + s[2] + s[3]; s[0] = r; }
    __syncthreads();
    r = s[0];
    __syncthreads();
    return r;
}

__device__ inline int blockReduceMaxI(int v, int* s) {
    for (int off = 32; off; off >>= 1) v = max(v, __shfl_down(v, off));
    int tid = threadIdx.x, wid = tid >> 6;
    if ((tid & 63) == 0) s[wid] = v;
    __syncthreads();
    int r;
    if (tid == 0) { r = max(max(s[0], s[1]), max(s[2], s[3])); s[0] = r; }
    __syncthreads();
    r = s[0];
    __syncthreads();
    return r;
}

// ---------------------------------------------------------------------------
// Kernel 1: fused fp32 -> {bf16, fp8 e4m3 (x16)} + row sq-norm; blocks >= N
// do labelinfo. (identical to R14/R16/R17 version — proven)
// ---------------------------------------------------------------------------
__global__ __launch_bounds__(256) void prep_kernel(const float* __restrict__ X,
                                                   ushort* __restrict__ Xbf,
                                                   uint32_t* __restrict__ Xb8,
                                                   float* __restrict__ sq,
                                                   const int* __restrict__ targets,
                                                   int* __restrict__ f1,
                                                   int* __restrict__ f2,
                                                   int* __restrict__ lcnt,
                                                   int D, int N) {
    __shared__ float sw[4];
    __shared__ int s1[4], s2[4], sc[4];
    int tid = threadIdx.x;
    int wid = tid >> 6;

    if (blockIdx.x >= (unsigned)N) {
        int lbl = blockIdx.x - N;
        int a1 = INT_MAX, a2 = INT_MAX, c = 0;
        for (int j = tid; j < N; j += 256) {
            if (targets[j] == lbl) {
                ++c;
                if (j < a1) { a2 = a1; a1 = j; }
                else if (j < a2) a2 = j;
            }
        }
        for (int off = 32; off; off >>= 1) {
            int b1 = __shfl_down(a1, off), b2 = __shfl_down(a2, off), bc = __shfl_down(c, off);
            int m1 = min(a1, b1);
            int m2 = min(max(a1, b1), min(a2, b2));
            a1 = m1; a2 = m2; c += bc;
        }
        if ((tid & 63) == 0) { s1[wid] = a1; s2[wid] = a2; sc[wid] = c; }
        __syncthreads();
        if (tid == 0) {
            int r1 = s1[0], r2 = s2[0], rc = sc[0];
            for (int w = 1; w < 4; ++w) {
                int m1 = min(r1, s1[w]);
                int m2 = min(max(r1, s1[w]), min(r2, s2[w]));
                r1 = m1; r2 = m2; rc += sc[w];
            }
            f1[lbl] = r1; f2[lbl] = r2; lcnt[lbl] = rc;
        }
        return;
    }

    int row = blockIdx.x;
    const float4* xr = reinterpret_cast<const float4*>(X + (size_t)row * D);
    ushort4* xo = reinterpret_cast<ushort4*>(Xbf + (size_t)row * D);
    uint32_t* x8o = Xb8 + (size_t)row * (D / 4);
    float s = 0.f;
    for (int c = tid; c < D / 4; c += 256) {
        float4 v = xr[c];
        s += v.x * v.x + v.y * v.y + v.z * v.z + v.w * v.w;
        ushort4 o;
        uint32_t b;
        b = __builtin_bit_cast(uint32_t, v.x); o.x = (ushort)((b + 0x7FFF + ((b >> 16) & 1)) >> 16);
        b = __builtin_bit_cast(uint32_t, v.y); o.y = (ushort)((b + 0x7FFF + ((b >> 16) & 1)) >> 16);
        b = __builtin_bit_cast(uint32_t, v.z); o.z = (ushort)((b + 0x7FFF + ((b >> 16) & 1)) >> 16);
        b = __builtin_bit_cast(uint32_t, v.w); o.w = (ushort)((b + 0x7FFF + ((b >> 16) & 1)) >> 16);
        xo[c] = o;
        // fp8 e4m3 of 16*x (e4m3 sweet spot); GEMM epilogue divides acc by 256
        int pk = __builtin_amdgcn_cvt_pk_fp8_f32(v.x * 16.f, v.y * 16.f, 0, false);
        pk = __builtin_amdgcn_cvt_pk_fp8_f32(v.z * 16.f, v.w * 16.f, pk, true);
        x8o[c] = (uint32_t)pk;
    }
    for (int off = 32; off; off >>= 1) s += __shfl_down(s, off);
    if ((tid & 63) == 0) sw[wid] = s;
    __syncthreads();
    if (tid == 0) sq[row] = sw[0] + sw[1] + sw[2] + sw[3];
}

// ---------------------------------------------------------------------------
// Kernel 2: 256x256-tile fp8 MFMA GEMM — R13's ring-2 counted-vmcnt loop
// (best measured GEMM: 62-70 us) with R16/R17's fused single-push scatter
// replacing the tileList bulk-write (no bin kernel). All geometry verbatim
// from R13 (proven); only the post-loop epilogue differs.
// ---------------------------------------------------------------------------
#define GBM 256
#define GBK 128
__global__ __launch_bounds__(512, 2) void distgemm_mfma(const uint8_t* __restrict__ Xb8,
                                                        const float* __restrict__ sq,
                                                        float2* __restrict__ cand,
                                                        int* __restrict__ cntArr,
                                                        int* __restrict__ needFB,
                                                        int N, int D) {
    __shared__ uint8_t As[2][GBM * GBK];   // 2 x 32 KB
    __shared__ uint8_t Bs[2][GBM * GBK];   // 2 x 32 KB
    __shared__ float2 tlist[TCAP];         // 13 KB
    __shared__ int s_cnt;

    // XCD swizzle: 256 blocks, 8 XCDs -> 32 consecutive wgids per XCD.
    int wg = blockIdx.x;
    int wgid = (wg & 7) * 32 + (wg >> 3);
    int by = wgid >> 4, bx = wgid & 15;

    int tid = threadIdx.x;
    int lane = tid & 63;
    int wave = tid >> 6;        // 0..7
    int waveM = wave >> 2;      // 0..1  -> 128-row half
    int waveN = wave & 3;       // 0..3  -> 64-col quarter

    int rowBase = by * GBM;
    int colBase = bx * GBM;

    if (tid == 0) s_cnt = 0;

    f32x4 acc[8][4];
#pragma unroll
    for (int m = 0; m < 8; ++m)
#pragma unroll
        for (int n2 = 0; n2 < 4; ++n2) {
            f32x4 z = {0.f, 0.f, 0.f, 0.f};
            acc[m][n2] = z;
        }

    // staging: per K-tile 32KB A + 32KB B; 8 loads/wave (4 rounds x {A,B}).
    int srow = lane >> 3;                              // 0..7, == row&7
    int sgb = ((lane & 7) << 4) ^ (srow << 4);         // swizzled source byte in row
    auto STAGE = [&](int buf, int k0) {
#pragma unroll
        for (int p = 0; p < 4; ++p) {
            int r = p * 64 + wave * 8 + srow;
            const uint8_t* gA = Xb8 + (size_t)(rowBase + r) * D + k0 + sgb;
            const uint8_t* gB = Xb8 + (size_t)(colBase + r) * D + k0 + sgb;
            uint8_t* dA = &As[buf][p * 8192 + wave * 1024];   // + lane*16 implicit
            uint8_t* dB = &Bs[buf][p * 8192 + wave * 1024];
            __builtin_amdgcn_global_load_lds(GLB_PTR(gA), LDS_PTR(dA), 16, 0, 0);
            __builtin_amdgcn_global_load_lds(GLB_PTR(gB), LDS_PTR(dB), 16, 0, 0);
        }
    };

    int nt = D / GBK;   // 8
    STAGE(0, 0);
    STAGE(1, GBK);

    int l15 = lane & 15;
    int kq32 = (lane >> 4) * 32;          // k-byte quarter base
    int rswz = (l15 & 7) << 4;            // (row&7)<<4, uniform across frags

    for (int t = 0; t < nt; ++t) {
        if (t < nt - 1) {
            asm volatile("s_waitcnt vmcnt(8)" ::: "memory");
        } else {
            asm volatile("s_waitcnt vmcnt(0)" ::: "memory");
        }
        __builtin_amdgcn_sched_barrier(0);
        asm volatile("s_barrier" ::: "memory");   // all waves' tile-t loads done

        const uint8_t* aB = As[t & 1];
        const uint8_t* bB = Bs[t & 1];

        __builtin_amdgcn_s_setprio(1);
        i32x8 bF[4];
#pragma unroll
        for (int n2 = 0; n2 < 4; ++n2) {
            int brl = waveN * 64 + n2 * 16 + l15;
            const uint8_t* base = bB + brl * 128;
            i32x4 lo = *reinterpret_cast<const i32x4*>(base + ((kq32) ^ rswz));
            i32x4 hi = *reinterpret_cast<const i32x4*>(base + ((kq32 + 16) ^ rswz));
            i32x8 f = {lo[0], lo[1], lo[2], lo[3], hi[0], hi[1], hi[2], hi[3]};
            bF[n2] = f;
        }
#pragma unroll
        for (int m = 0; m < 8; ++m) {
            int arl = waveM * 128 + m * 16 + l15;
            const uint8_t* base = aB + arl * 128;
            i32x4 lo = *reinterpret_cast<const i32x4*>(base + ((kq32) ^ rswz));
            i32x4 hi = *reinterpret_cast<const i32x4*>(base + ((kq32 + 16) ^ rswz));
            i32x8 aF = {lo[0], lo[1], lo[2], lo[3], hi[0], hi[1], hi[2], hi[3]};
#pragma unroll
            for (int n2 = 0; n2 < 4; ++n2)
                acc[m][n2] = __builtin_amdgcn_mfma_scale_f32_16x16x128_f8f6f4(
                    aF, bF[n2], acc[m][n2], 0, 0, 0, 0x7F, 0, 0x7F);
        }
        __builtin_amdgcn_s_setprio(0);

        asm volatile("s_barrier" ::: "memory");   // all waves done reading slot
        if (t + 2 < nt) STAGE(t & 1, (t + 2) * GBK);
    }

    __syncthreads();   // tlist/s_cnt shared from here

    // epilogue: acc = 256*dot -> v = sqi+sqj-2*dot = sqi+sqj-acc/128
    int cr = (lane >> 4) * 4;
    int cc = lane & 15;
    unsigned long long lmask_lt = (1ull << lane) - 1ull;
#pragma unroll
    for (int m = 0; m < 8; ++m) {
#pragma unroll
        for (int n2 = 0; n2 < 4; ++n2) {
            int gcol = colBase + waveN * 64 + n2 * 16 + cc;
            float sqc = sq[gcol];
#pragma unroll
            for (int r = 0; r < 4; ++r) {
                int grow = rowBase + waveM * 128 + m * 16 + cr + r;
                float v = sq[grow] + sqc - acc[m][n2][r] * 0.0078125f;  // 2/256
                bool pred = (v < P0SQ) && (grow != gcol);
                unsigned long long mask = __ballot(pred);
                if (mask) {
                    int leader = __ffsll((long long)mask) - 1;
                    int tot = __popcll(mask);
                    int base = 0;
                    if (lane == leader) base = atomicAdd(&s_cnt, tot);
                    base = __shfl(base, leader);
                    if (pred) {
                        int idx = base + __popcll(mask & lmask_lt);
                        if (idx < TCAP) {
                            float d = sqrtf(fmaxf(v, 1e-12f));
                            uint32_t pk = ((uint32_t)grow << 12) | (uint32_t)gcol;
                            float2 e; e.x = d; e.y = __builtin_bit_cast(float, pk);
                            tlist[idx] = e;
                        }
                    }
                }
            }
        }
    }
    __syncthreads();

    // fused scatter: single push per record to row-side list; the transposed
    // tile (bx,by) supplies the mirror record (full grid). (R16/R17-proven)
    int cnt = min(s_cnt, TCAP);
    for (int e = tid; e < cnt; e += 512) {
        float2 v = tlist[e];
        uint32_t pk = __builtin_bit_cast(uint32_t, v.y);
        int i = (int)(pk >> 12), j = (int)(pk & 4095u);
        int p = atomicAdd(&cntArr[i], 1);
        if (p < CAP) {
            float2 e1; e1.x = v.x; e1.y = __builtin_bit_cast(float, j);
            cand[(size_t)i * CAP + p] = e1;
        }
    }
    if (s_cnt > TCAP && tid < GBM)   // astronomically unlikely; rows lose records
        needFB[rowBase + tid] = 1;
}

// ---------------------------------------------------------------------------
// Kernel 3: per-row finalize from candidate lists. One WAVE per row (4/block).
// (identical to R14/R16/R17 version — proven)
// ---------------------------------------------------------------------------
__global__ __launch_bounds__(256) void rowfinal_kernel(const float2* __restrict__ cand,
                                                       const int* __restrict__ cntArr,
                                                       const int* __restrict__ targets,
                                                       const ushort* __restrict__ Xbf,
                                                       const float* __restrict__ sq,
                                                       const int* __restrict__ f1,
                                                       const int* __restrict__ f2,
                                                       const int* __restrict__ lcnt,
                                                       int* __restrict__ needFB,
                                                       float* __restrict__ rowLoss,
                                                       int N, int D) {
    __shared__ float dbuf[4][CAP];
    int tid = threadIdx.x, lane = tid & 63, w = tid >> 6;
    int row = blockIdx.x * 4 + w;
    int ti = targets[row];
    int lc = lcnt[ti];
    bool validRow = (lc >= 2) && (lc < N);
    int cnt = cntArr[row];
    bool fb = (cnt < KSEL + 1) || (cnt > CAP);
    int lim = fb ? 0 : cnt;

    float ed[4]; int ej[4];
#pragma unroll
    for (int s = 0; s < 4; ++s) {
        int idx = lane + s * 64;
        bool in = (!fb) && (idx < cnt);
        if (in) {
            float2 e = cand[(size_t)row * CAP + idx];
            ed[s] = e.x; ej[s] = __builtin_bit_cast(int, e.y);
            dbuf[w][idx] = e.x;
        } else { ed[s] = BIGV; ej[s] = -1; }
    }
    __syncthreads();

    // exact rank: thr = value at rank KSEL (0-based) among candidates
    int rlo[4] = {0, 0, 0, 0}, req[4] = {0, 0, 0, 0};
    for (int q = 0; q < lim; ++q) {
        float u = dbuf[w][q];
#pragma unroll
        for (int s = 0; s < 4; ++s) {
            rlo[s] += (u < ed[s]);
            req[s] += (u == ed[s]);
        }
    }
    float thrc = BIGV;
#pragma unroll
    for (int s = 0; s < 4; ++s)
        if (ej[s] >= 0 && rlo[s] <= KSEL && KSEL < rlo[s] + req[s]) thrc = fminf(thrc, ed[s]);
    for (int off = 32; off; off >>= 1) thrc = fminf(thrc, __shfl_down(thrc, off));
    float thr = __shfl(thrc, 0);

    // masked sums over candidates (below-thr set fully contained in list)
    float posS = 0.f, negS = 0.f;
    int apb = 0;
#pragma unroll
    for (int s = 0; s < 4; ++s) {
        if (ej[s] >= 0 && ed[s] < thr) {
            bool same = (targets[ej[s]] == ti);
            float e = expf(ALPHA * (1.0f - ed[s]));
            if (same) { posS += e; apb = 1; }
            else negS += e;
        }
    }
    for (int off = 32; off; off >>= 1) {
        posS += __shfl_down(posS, off);
        negS += __shfl_down(negS, off);
        apb = max(apb, __shfl_down(apb, off));
    }

    // first-positive fallback distance (bf16 dot, fp32 accum)
    int fp = 0;
    float dot = 0.f;
    if (validRow) {
        fp = (row == f1[ti]) ? f2[ti] : f1[ti];
        const ushort* xr = Xbf + (size_t)row * D;
        const ushort* xf = Xbf + (size_t)fp * D;
        for (int c = lane; c < D / 4; c += 64) {
            ushort4 a = *reinterpret_cast<const ushort4*>(xr + (size_t)c * 4);
            ushort4 b = *reinterpret_cast<const ushort4*>(xf + (size_t)c * 4);
            dot += bfval(a.x) * bfval(b.x) + bfval(a.y) * bfval(b.y)
                 + bfval(a.z) * bfval(b.z) + bfval(a.w) * bfval(b.w);
        }
    }
    for (int off = 32; off; off >>= 1) dot += __shfl_down(dot, off);

    if (lane == 0) {
        if (fb) {
            needFB[row] = 1;
        } else if (!validRow) {
            rowLoss[row] = BIGV;
        } else {
            float fbD = sqrtf(fmaxf(sq[row] + sq[fp] - 2.0f * dot, 1e-12f));
            float posLogit = apb ? posS : expf(ALPHA * (1.0f - fbD));
            rowLoss[row] = -logf(posLogit / (posLogit + negS));
        }
    }
}

// ---------------------------------------------------------------------------
// Kernel 4: exact fallback (full-row recompute, bf16). Expected zero work.
// (identical to R14/R16/R17 version — proven)
// ---------------------------------------------------------------------------
__global__ __launch_bounds__(256) void fallback_kernel(const ushort* __restrict__ Xbf,
                                                       const float* __restrict__ sq,
                                                       const int* __restrict__ targets,
                                                       const int* __restrict__ needFB,
                                                       const int* __restrict__ f1,
                                                       const int* __restrict__ f2,
                                                       const int* __restrict__ lcnt,
                                                       float* __restrict__ rowLoss,
                                                       int N, int D) {
    int row = blockIdx.x;
    if (!needFB[row]) return;

    __shared__ float xrow[1024];
    __shared__ float rowD[NMAX];
    __shared__ float sF[4];
    __shared__ int sI[4];
    int tid = threadIdx.x;

    for (int k = tid; k < D; k += 256) xrow[k] = bfval(Xbf[(size_t)row * D + k]);
    __syncthreads();

    for (int j = tid; j < N; j += 256) {
        float dot = 0.f;
        const ushort* xj = Xbf + (size_t)j * D;
        for (int k = 0; k < D; ++k) dot += xrow[k] * bfval(xj[k]);
        rowD[j] = (j == row) ? BIGV
                             : sqrtf(fmaxf(sq[row] + sq[j] - 2.0f * dot, 1e-12f));
    }
    __syncthreads();

    uint32_t lo = 0, hi = 0x40800000u;
    while (lo < hi) {
        uint32_t mid = (lo + hi) >> 1;
        float mv = __builtin_bit_cast(float, mid);
        int c = 0;
        for (int j = tid; j < N; j += 256) c += (rowD[j] <= mv);
        c = blockReduceSumI(c, sI);
        if (c >= KSEL + 1) hi = mid; else lo = mid + 1;
    }
    float thr = __builtin_bit_cast(float, hi);

    int ti = targets[row];
    int lc = lcnt[ti];
    bool validRow = (lc >= 2) && (lc < N);

    float posS = 0.f, negS = 0.f;
    int apb = 0;
    for (int j = tid; j < N; j += 256) {
        if (j == row) continue;
        float d = rowD[j];
        bool same = (targets[j] == ti);
        if (d < thr) {
            float e = expf(ALPHA * (1.0f - d));
            if (same) { posS += e; apb = 1; }
            else negS += e;
        }
    }
    posS = blockReduceSumF(posS, sF);
    negS = blockReduceSumF(negS, sF);
    apb = blockReduceMaxI(apb, sI);

    if (tid == 0) {
        if (!validRow) { rowLoss[row] = BIGV; return; }
        int fp = (row == f1[ti]) ? f2[ti] : f1[ti];
        float posLogit = apb ? posS : expf(ALPHA * (1.0f - rowD[fp]));
        rowLoss[row] = -logf(posLogit / (posLogit + negS));
    }
}

// ---------------------------------------------------------------------------
// Kernel 5: single-block reduction over rowLoss -> out[4]
// ---------------------------------------------------------------------------
__global__ __launch_bounds__(256) void reduce_kernel(const float* __restrict__ rowLoss,
                                                     float* __restrict__ out, int N) {
    __shared__ float sF[4];
    __shared__ int sI[4];
    int tid = threadIdx.x;
    float sumL = 0.f;
    int nValid = 0, nAcc = 0;
    for (int j = tid; j < N; j += 256) {
        float L = rowLoss[j];
        if (L != BIGV) {
            sumL += L;
            ++nValid;
            if (L < 0.6f) ++nAcc;
        }
    }
    sumL = blockReduceSumF(sumL, sF);
    nValid = blockReduceSumI(nValid, sI);
    nAcc = blockReduceSumI(nAcc, sI);
    if (tid == 0) {
        out[0] = (nValid > 0) ? sumL / (float)nValid : 0.f;
        out[1] = (float)nAcc / (float)N;
        out[2] = 0.f;
        out[3] = 0.f;
    }
}

// ---------------------------------------------------------------------------
extern "C" void kernel_launch(void* const* d_in, const int* in_sizes, int n_in,
                              void* d_out, int out_size, void* d_ws, size_t ws_size,
                              hipStream_t stream) {
    const float* X = (const float*)d_in[0];
    const int* targets = (const int*)d_in[1];
    float* out = (float*)d_out;

    int N = in_sizes[1];             // 4096
    int D = in_sizes[0] / N;         // 1024
    int tiles = N / GBM;             // 16
    int nTiles = tiles * tiles;      // 256

    // 8B-aligned float2 array first
    float2* cand     = (float2*)d_ws;                          // N*CAP f2 (7.3 MB)
    float*  sq       = (float*)(cand + (size_t)N * CAP);
    float*  rowLoss  = sq + N;
    int*    cntArr   = (int*)(rowLoss + N);
    int*    needFB   = cntArr + N;
    int*    f1       = needFB + N;
    int*    f2       = f1 + 64;
    int*    lcnt     = f2 + 64;
    ushort* Xbf      = (ushort*)(lcnt + 64 + 64);              // N*D bf16 (8 MB)
    uint32_t* Xb8    = (uint32_t*)(Xbf + (size_t)N * D);       // N*D fp8  (4 MB)

    hipMemsetAsync(cntArr, 0, N * sizeof(int), stream);
    hipMemsetAsync(needFB, 0, N * sizeof(int), stream);

    prep_kernel<<<N + 64, 256, 0, stream>>>(X, Xbf, Xb8, sq, targets,
                                            f1, f2, lcnt, D, N);

    distgemm_mfma<<<nTiles, 512, 0, stream>>>((const uint8_t*)Xb8, sq, cand,
                                              cntArr, needFB, N, D);

    rowfinal_kernel<<<N / 4, 256, 0, stream>>>(cand, cntArr, targets, Xbf, sq,
                                               f1, f2, lcnt, needFB, rowLoss, N, D);

    fallback_kernel<<<N, 256, 0, stream>>>(Xbf, sq, targets, needFB,
                                           f1, f2, lcnt, rowLoss, N, D);

    reduce_kernel<<<1, 256, 0, stream>>>(rowLoss, out, N);
}

// Round 19
// 108.872 us; speedup vs baseline: 1.1745x; 1.0492x over previous
//
#include <hip/hip_runtime.h>
#include <hip/hip_bf16.h>
#include <cfloat>
#include <climits>
#include <cstdint>

#define ALPHA 30.0f
#define KSEL 16          // threshold = sorted[:,16] (17th smallest off-diag)
#define P0 1.368f        // candidate cutoff: E[cnt/row]≈82, P(cnt<17)~1e-13
#define P0SQ (P0 * P0)
#define CAP 224          // per-row candidate capacity (mean 82, +15 sigma)
#define TCAP 512         // per-tile candidate capacity (128² tile: mean 328, +10 sigma)
#define BIGV 1e30f
#define NMAX 4096

typedef __attribute__((ext_vector_type(4))) float f32x4;
typedef __attribute__((ext_vector_type(8))) int i32x8;
typedef __attribute__((ext_vector_type(4))) int i32x4;

#define LDS_PTR(p) ((__attribute__((address_space(3))) uint32_t*)(p))
#define GLB_PTR(p) ((const __attribute__((address_space(1))) uint32_t*)(p))

__device__ inline float bfval(ushort u) {
    return __builtin_bit_cast(float, (uint32_t)u << 16);
}

// ---------------------------------------------------------------------------
// block reduce helpers (256 threads, 4 waves)
// ---------------------------------------------------------------------------
__device__ inline float blockReduceSumF(float v, float* s) {
    for (int off = 32; off; off >>= 1) v += __shfl_down(v, off);
    int tid = threadIdx.x, wid = tid >> 6;
    if ((tid & 63) == 0) s[wid] = v;
    __syncthreads();
    float r;
    if (tid == 0) { r = s[0] + s[1] + s[2] + s[3]; s[0] = r; }
    __syncthreads();
    r = s[0];
    __syncthreads();
    return r;
}

__device__ inline int blockReduceSumI(int v, int* s) {
    for (int off = 32; off; off >>= 1) v += __shfl_down(v, off);
    int tid = threadIdx.x, wid = tid >> 6;
    if ((tid & 63) == 0) s[wid] = v;
    __syncthreads();
    int r;
    if (tid == 0) { r = s[0] + s[1] + s[2] + s[3]; s[0] = r; }
    __syncthreads();
    r = s[0];
    __syncthreads();
    return r;
}

__device__ inline int blockReduceMaxI(int v, int* s) {
    for (int off = 32; off; off >>= 1) v = max(v, __shfl_down(v, off));
    int tid = threadIdx.x, wid = tid >> 6;
    if ((tid & 63) == 0) s[wid] = v;
    __syncthreads();
    int r;
    if (tid == 0) { r = max(max(s[0], s[1]), max(s[2], s[3])); s[0] = r; }
    __syncthreads();
    r = s[0];
    __syncthreads();
    return r;
}

// ---------------------------------------------------------------------------
// Kernel 1: fused fp32 -> {bf16, fp8 e4m3 (x16)} + row sq-norm + per-row
// zeroing of cntArr/needFB (replaces two hipMemsetAsync launches);
// blocks >= N do labelinfo. Otherwise identical to R16 (proven).
// ---------------------------------------------------------------------------
__global__ __launch_bounds__(256) void prep_kernel(const float* __restrict__ X,
                                                   ushort* __restrict__ Xbf,
                                                   uint32_t* __restrict__ Xb8,
                                                   float* __restrict__ sq,
                                                   const int* __restrict__ targets,
                                                   int* __restrict__ f1,
                                                   int* __restrict__ f2,
                                                   int* __restrict__ lcnt,
                                                   int* __restrict__ cntArr,
                                                   int* __restrict__ needFB,
                                                   int D, int N) {
    __shared__ float sw[4];
    __shared__ int s1[4], s2[4], sc[4];
    int tid = threadIdx.x;
    int wid = tid >> 6;

    if (blockIdx.x >= (unsigned)N) {
        int lbl = blockIdx.x - N;
        int a1 = INT_MAX, a2 = INT_MAX, c = 0;
        for (int j = tid; j < N; j += 256) {
            if (targets[j] == lbl) {
                ++c;
                if (j < a1) { a2 = a1; a1 = j; }
                else if (j < a2) a2 = j;
            }
        }
        for (int off = 32; off; off >>= 1) {
            int b1 = __shfl_down(a1, off), b2 = __shfl_down(a2, off), bc = __shfl_down(c, off);
            int m1 = min(a1, b1);
            int m2 = min(max(a1, b1), min(a2, b2));
            a1 = m1; a2 = m2; c += bc;
        }
        if ((tid & 63) == 0) { s1[wid] = a1; s2[wid] = a2; sc[wid] = c; }
        __syncthreads();
        if (tid == 0) {
            int r1 = s1[0], r2 = s2[0], rc = sc[0];
            for (int w = 1; w < 4; ++w) {
                int m1 = min(r1, s1[w]);
                int m2 = min(max(r1, s1[w]), min(r2, s2[w]));
                r1 = m1; r2 = m2; rc += sc[w];
            }
            f1[lbl] = r1; f2[lbl] = r2; lcnt[lbl] = rc;
        }
        return;
    }

    int row = blockIdx.x;
    if (tid == 0) { cntArr[row] = 0; needFB[row] = 0; }
    const float4* xr = reinterpret_cast<const float4*>(X + (size_t)row * D);
    ushort4* xo = reinterpret_cast<ushort4*>(Xbf + (size_t)row * D);
    uint32_t* x8o = Xb8 + (size_t)row * (D / 4);
    float s = 0.f;
    for (int c = tid; c < D / 4; c += 256) {
        float4 v = xr[c];
        s += v.x * v.x + v.y * v.y + v.z * v.z + v.w * v.w;
        ushort4 o;
        uint32_t b;
        b = __builtin_bit_cast(uint32_t, v.x); o.x = (ushort)((b + 0x7FFF + ((b >> 16) & 1)) >> 16);
        b = __builtin_bit_cast(uint32_t, v.y); o.y = (ushort)((b + 0x7FFF + ((b >> 16) & 1)) >> 16);
        b = __builtin_bit_cast(uint32_t, v.z); o.z = (ushort)((b + 0x7FFF + ((b >> 16) & 1)) >> 16);
        b = __builtin_bit_cast(uint32_t, v.w); o.w = (ushort)((b + 0x7FFF + ((b >> 16) & 1)) >> 16);
        xo[c] = o;
        // fp8 e4m3 of 16*x (e4m3 sweet spot); GEMM epilogue divides acc by 256
        int pk = __builtin_amdgcn_cvt_pk_fp8_f32(v.x * 16.f, v.y * 16.f, 0, false);
        pk = __builtin_amdgcn_cvt_pk_fp8_f32(v.z * 16.f, v.w * 16.f, pk, true);
        x8o[c] = (uint32_t)pk;
    }
    for (int off = 32; off; off >>= 1) s += __shfl_down(s, off);
    if ((tid & 63) == 0) sw[wid] = s;
    __syncthreads();
    if (tid == 0) sq[row] = sw[0] + sw[1] + sw[2] + sw[3];
}

// ---------------------------------------------------------------------------
// Kernel 2: 128x128-tile fp8 MFMA GEMM (mfma_scale 16x16x128, neutral scale).
// Upper-triangle via grid(32,32) + early-exit. 4 waves, single-buffer
// 2-barrier loop, T2 swizzle (linear LDS dest + inverse-swizzled global
// source). Candidates ballot-compacted to tlist, fused dual-push scatter.
// (identical to R16 — best measured total)
// ---------------------------------------------------------------------------
#define GBM 128
#define GBK 128
__global__ __launch_bounds__(256) void distgemm_mfma(const uint8_t* __restrict__ Xb8,
                                                     const float* __restrict__ sq,
                                                     float2* __restrict__ cand,
                                                     int* __restrict__ cntArr,
                                                     int* __restrict__ needFB,
                                                     int N, int D) {
    if (blockIdx.x < blockIdx.y) return;   // upper triangle only (bx >= by)
    __shared__ uint8_t As[GBM * GBK];    // 16 KB
    __shared__ uint8_t Bs[GBM * GBK];    // 16 KB
    __shared__ float2 tlist[TCAP];       // 4 KB
    __shared__ int s_cnt;

    int by = blockIdx.y, bx = blockIdx.x;
    bool diag = (bx == by);

    int tid = threadIdx.x;
    int lane = tid & 63;
    int wave = tid >> 6;       // 0..3
    int waveR = wave >> 1;     // 0..1
    int waveC = wave & 1;      // 0..1

    int rowBase = by * GBM;
    int colBase = bx * GBM;

    if (tid == 0) s_cnt = 0;

    f32x4 acc[4][4];
#pragma unroll
    for (int m = 0; m < 4; ++m)
#pragma unroll
        for (int n2 = 0; n2 < 4; ++n2) {
            f32x4 z = {0.f, 0.f, 0.f, 0.f};
            acc[m][n2] = z;
        }

    // staging: A(16KB)+B(16KB) per K-tile; 16 chunks of 1KB; wave does 4.
    int srow = lane >> 3;                          // 0..7, == row&7
    int sgb = ((lane & 7) << 4) ^ (srow << 4);     // swizzled source byte in row
    auto STAGE = [&](int k0) {
#pragma unroll
        for (int p = 0; p < 4; ++p) {
            int c = wave * 4 + p;                  // 0..15
            int r = c * 8 + srow;                  // 0..127
            const uint8_t* gA = Xb8 + (size_t)(rowBase + r) * D + k0 + sgb;
            const uint8_t* gB = Xb8 + (size_t)(colBase + r) * D + k0 + sgb;
            __builtin_amdgcn_global_load_lds(GLB_PTR(gA), LDS_PTR(&As[c * 1024]), 16, 0, 0);
            __builtin_amdgcn_global_load_lds(GLB_PTR(gB), LDS_PTR(&Bs[c * 1024]), 16, 0, 0);
        }
    };

    int l15 = lane & 15;
    int kq32 = (lane >> 4) * 32;          // k-byte quarter base
    int rswz = (l15 & 7) << 4;            // (row&7)<<4, uniform across frags
    int nt = D / GBK;                     // 8

    for (int t = 0; t < nt; ++t) {
        STAGE(t * GBK);
        __syncthreads();   // drains vmcnt(0): tile staged & visible

        i32x8 bF[4];
#pragma unroll
        for (int n2 = 0; n2 < 4; ++n2) {
            int brl = waveC * 64 + n2 * 16 + l15;
            const uint8_t* base = Bs + brl * 128;
            i32x4 lo = *reinterpret_cast<const i32x4*>(base + ((kq32) ^ rswz));
            i32x4 hi = *reinterpret_cast<const i32x4*>(base + ((kq32 + 16) ^ rswz));
            i32x8 f = {lo[0], lo[1], lo[2], lo[3], hi[0], hi[1], hi[2], hi[3]};
            bF[n2] = f;
        }
        __builtin_amdgcn_s_setprio(1);
#pragma unroll
        for (int m = 0; m < 4; ++m) {
            int arl = waveR * 64 + m * 16 + l15;
            const uint8_t* base = As + arl * 128;
            i32x4 lo = *reinterpret_cast<const i32x4*>(base + ((kq32) ^ rswz));
            i32x4 hi = *reinterpret_cast<const i32x4*>(base + ((kq32 + 16) ^ rswz));
            i32x8 aF = {lo[0], lo[1], lo[2], lo[3], hi[0], hi[1], hi[2], hi[3]};
#pragma unroll
            for (int n2 = 0; n2 < 4; ++n2)
                acc[m][n2] = __builtin_amdgcn_mfma_scale_f32_16x16x128_f8f6f4(
                    aF, bF[n2], acc[m][n2], 0, 0, 0, 0x7F, 0, 0x7F);
        }
        __builtin_amdgcn_s_setprio(0);
        __syncthreads();   // all waves done reading before next overwrite
    }

    // epilogue: acc = 256*dot -> v = sqi+sqj-2*dot = sqi+sqj-acc/128
    int cr = (lane >> 4) * 4;
    int cc = lane & 15;
    unsigned long long lmask_lt = (1ull << lane) - 1ull;
#pragma unroll
    for (int m = 0; m < 4; ++m) {
#pragma unroll
        for (int n2 = 0; n2 < 4; ++n2) {
            int gcol = colBase + waveC * 64 + n2 * 16 + cc;
            float sqc = sq[gcol];
#pragma unroll
            for (int r = 0; r < 4; ++r) {
                int grow = rowBase + waveR * 64 + m * 16 + cr + r;
                float v = sq[grow] + sqc - acc[m][n2][r] * 0.0078125f;  // 2/256
                bool pred = (v < P0SQ) && (grow != gcol);
                unsigned long long mask = __ballot(pred);
                if (mask) {
                    int leader = __ffsll((long long)mask) - 1;
                    int tot = __popcll(mask);
                    int base = 0;
                    if (lane == leader) base = atomicAdd(&s_cnt, tot);
                    base = __shfl(base, leader);
                    if (pred) {
                        int idx = base + __popcll(mask & lmask_lt);
                        if (idx < TCAP) {
                            float d = sqrtf(fmaxf(v, 1e-12f));
                            uint32_t pk = ((uint32_t)grow << 12) | (uint32_t)gcol;
                            float2 e; e.x = d; e.y = __builtin_bit_cast(float, pk);
                            tlist[idx] = e;
                        }
                    }
                }
            }
        }
    }
    __syncthreads();

    // fused scatter: push records straight to per-row candidate lists.
    // off-diag tiles dual-push (i,j)&(j,i); diag tiles see both orders already.
    int cnt = min(s_cnt, TCAP);
    for (int e = tid; e < cnt; e += 256) {
        float2 v = tlist[e];
        uint32_t pk = __builtin_bit_cast(uint32_t, v.y);
        int i = (int)(pk >> 12), j = (int)(pk & 4095u);
        int p = atomicAdd(&cntArr[i], 1);
        if (p < CAP) {
            float2 e1; e1.x = v.x; e1.y = __builtin_bit_cast(float, j);
            cand[(size_t)i * CAP + p] = e1;
        }
        if (!diag) {
            int q = atomicAdd(&cntArr[j], 1);
            if (q < CAP) {
                float2 e2; e2.x = v.x; e2.y = __builtin_bit_cast(float, i);
                cand[(size_t)j * CAP + q] = e2;
            }
        }
    }
    if (s_cnt > TCAP) {   // astronomically unlikely; exact fallback covers it
        if (tid < GBM) needFB[rowBase + tid] = 1;
        else needFB[colBase + tid - GBM] = 1;
    }
}

// ---------------------------------------------------------------------------
// Kernel 3: per-row finalize from candidate lists. One WAVE per row (4/block).
// (identical to R14/R16 version — proven)
// ---------------------------------------------------------------------------
__global__ __launch_bounds__(256) void rowfinal_kernel(const float2* __restrict__ cand,
                                                       const int* __restrict__ cntArr,
                                                       const int* __restrict__ targets,
                                                       const ushort* __restrict__ Xbf,
                                                       const float* __restrict__ sq,
                                                       const int* __restrict__ f1,
                                                       const int* __restrict__ f2,
                                                       const int* __restrict__ lcnt,
                                                       int* __restrict__ needFB,
                                                       float* __restrict__ rowLoss,
                                                       int N, int D) {
    __shared__ float dbuf[4][CAP];
    int tid = threadIdx.x, lane = tid & 63, w = tid >> 6;
    int row = blockIdx.x * 4 + w;
    int ti = targets[row];
    int lc = lcnt[ti];
    bool validRow = (lc >= 2) && (lc < N);
    int cnt = cntArr[row];
    bool fb = (cnt < KSEL + 1) || (cnt > CAP);
    int lim = fb ? 0 : cnt;

    float ed[4]; int ej[4];
#pragma unroll
    for (int s = 0; s < 4; ++s) {
        int idx = lane + s * 64;
        bool in = (!fb) && (idx < cnt);
        if (in) {
            float2 e = cand[(size_t)row * CAP + idx];
            ed[s] = e.x; ej[s] = __builtin_bit_cast(int, e.y);
            dbuf[w][idx] = e.x;
        } else { ed[s] = BIGV; ej[s] = -1; }
    }
    __syncthreads();

    // exact rank: thr = value at rank KSEL (0-based) among candidates
    int rlo[4] = {0, 0, 0, 0}, req[4] = {0, 0, 0, 0};
    for (int q = 0; q < lim; ++q) {
        float u = dbuf[w][q];
#pragma unroll
        for (int s = 0; s < 4; ++s) {
            rlo[s] += (u < ed[s]);
            req[s] += (u == ed[s]);
        }
    }
    float thrc = BIGV;
#pragma unroll
    for (int s = 0; s < 4; ++s)
        if (ej[s] >= 0 && rlo[s] <= KSEL && KSEL < rlo[s] + req[s]) thrc = fminf(thrc, ed[s]);
    for (int off = 32; off; off >>= 1) thrc = fminf(thrc, __shfl_down(thrc, off));
    float thr = __shfl(thrc, 0);

    // masked sums over candidates (below-thr set fully contained in list)
    float posS = 0.f, negS = 0.f;
    int apb = 0;
#pragma unroll
    for (int s = 0; s < 4; ++s) {
        if (ej[s] >= 0 && ed[s] < thr) {
            bool same = (targets[ej[s]] == ti);
            float e = expf(ALPHA * (1.0f - ed[s]));
            if (same) { posS += e; apb = 1; }
            else negS += e;
        }
    }
    for (int off = 32; off; off >>= 1) {
        posS += __shfl_down(posS, off);
        negS += __shfl_down(negS, off);
        apb = max(apb, __shfl_down(apb, off));
    }

    // first-positive fallback distance (bf16 dot, fp32 accum)
    int fp = 0;
    float dot = 0.f;
    if (validRow) {
        fp = (row == f1[ti]) ? f2[ti] : f1[ti];
        const ushort* xr = Xbf + (size_t)row * D;
        const ushort* xf = Xbf + (size_t)fp * D;
        for (int c = lane; c < D / 4; c += 64) {
            ushort4 a = *reinterpret_cast<const ushort4*>(xr + (size_t)c * 4);
            ushort4 b = *reinterpret_cast<const ushort4*>(xf + (size_t)c * 4);
            dot += bfval(a.x) * bfval(b.x) + bfval(a.y) * bfval(b.y)
                 + bfval(a.z) * bfval(b.z) + bfval(a.w) * bfval(b.w);
        }
    }
    for (int off = 32; off; off >>= 1) dot += __shfl_down(dot, off);

    if (lane == 0) {
        if (fb) {
            needFB[row] = 1;
        } else if (!validRow) {
            rowLoss[row] = BIGV;
        } else {
            float fbD = sqrtf(fmaxf(sq[row] + sq[fp] - 2.0f * dot, 1e-12f));
            float posLogit = apb ? posS : expf(ALPHA * (1.0f - fbD));
            rowLoss[row] = -logf(posLogit / (posLogit + negS));
        }
    }
}

// ---------------------------------------------------------------------------
// Kernel 4: exact fallback (full-row recompute, bf16). Expected zero work.
// (identical to R14/R16 version — proven)
// ---------------------------------------------------------------------------
__global__ __launch_bounds__(256) void fallback_kernel(const ushort* __restrict__ Xbf,
                                                       const float* __restrict__ sq,
                                                       const int* __restrict__ targets,
                                                       const int* __restrict__ needFB,
                                                       const int* __restrict__ f1,
                                                       const int* __restrict__ f2,
                                                       const int* __restrict__ lcnt,
                                                       float* __restrict__ rowLoss,
                                                       int N, int D) {
    int row = blockIdx.x;
    if (!needFB[row]) return;

    __shared__ float xrow[1024];
    __shared__ float rowD[NMAX];
    __shared__ float sF[4];
    __shared__ int sI[4];
    int tid = threadIdx.x;

    for (int k = tid; k < D; k += 256) xrow[k] = bfval(Xbf[(size_t)row * D + k]);
    __syncthreads();

    for (int j = tid; j < N; j += 256) {
        float dot = 0.f;
        const ushort* xj = Xbf + (size_t)j * D;
        for (int k = 0; k < D; ++k) dot += xrow[k] * bfval(xj[k]);
        rowD[j] = (j == row) ? BIGV
                             : sqrtf(fmaxf(sq[row] + sq[j] - 2.0f * dot, 1e-12f));
    }
    __syncthreads();

    uint32_t lo = 0, hi = 0x40800000u;
    while (lo < hi) {
        uint32_t mid = (lo + hi) >> 1;
        float mv = __builtin_bit_cast(float, mid);
        int c = 0;
        for (int j = tid; j < N; j += 256) c += (rowD[j] <= mv);
        c = blockReduceSumI(c, sI);
        if (c >= KSEL + 1) hi = mid; else lo = mid + 1;
    }
    float thr = __builtin_bit_cast(float, hi);

    int ti = targets[row];
    int lc = lcnt[ti];
    bool validRow = (lc >= 2) && (lc < N);

    float posS = 0.f, negS = 0.f;
    int apb = 0;
    for (int j = tid; j < N; j += 256) {
        if (j == row) continue;
        float d = rowD[j];
        bool same = (targets[j] == ti);
        if (d < thr) {
            float e = expf(ALPHA * (1.0f - d));
            if (same) { posS += e; apb = 1; }
            else negS += e;
        }
    }
    posS = blockReduceSumF(posS, sF);
    negS = blockReduceSumF(negS, sF);
    apb = blockReduceMaxI(apb, sI);

    if (tid == 0) {
        if (!validRow) { rowLoss[row] = BIGV; return; }
        int fp = (row == f1[ti]) ? f2[ti] : f1[ti];
        float posLogit = apb ? posS : expf(ALPHA * (1.0f - rowD[fp]));
        rowLoss[row] = -logf(posLogit / (posLogit + negS));
    }
}

// ---------------------------------------------------------------------------
// Kernel 5: single-block reduction over rowLoss -> out[4]
// ---------------------------------------------------------------------------
__global__ __launch_bounds__(256) void reduce_kernel(const float* __restrict__ rowLoss,
                                                     float* __restrict__ out, int N) {
    __shared__ float sF[4];
    __shared__ int sI[4];
    int tid = threadIdx.x;
    float sumL = 0.f;
    int nValid = 0, nAcc = 0;
    for (int j = tid; j < N; j += 256) {
        float L = rowLoss[j];
        if (L != BIGV) {
            sumL += L;
            ++nValid;
            if (L < 0.6f) ++nAcc;
        }
    }
    sumL = blockReduceSumF(sumL, sF);
    nValid = blockReduceSumI(nValid, sI);
    nAcc = blockReduceSumI(nAcc, sI);
    if (tid == 0) {
        out[0] = (nValid > 0) ? sumL / (float)nValid : 0.f;
        out[1] = (float)nAcc / (float)N;
        out[2] = 0.f;
        out[3] = 0.f;
    }
}

// ---------------------------------------------------------------------------
extern "C" void kernel_launch(void* const* d_in, const int* in_sizes, int n_in,
                              void* d_out, int out_size, void* d_ws, size_t ws_size,
                              hipStream_t stream) {
    const float* X = (const float*)d_in[0];
    const int* targets = (const int*)d_in[1];
    float* out = (float*)d_out;

    int N = in_sizes[1];             // 4096
    int D = in_sizes[0] / N;         // 1024
    int tiles = N / GBM;             // 32

    // 8B-aligned float2 array first
    float2* cand     = (float2*)d_ws;                          // N*CAP f2 (7.3 MB)
    float*  sq       = (float*)(cand + (size_t)N * CAP);
    float*  rowLoss  = sq + N;
    int*    cntArr   = (int*)(rowLoss + N);
    int*    needFB   = cntArr + N;
    int*    f1       = needFB + N;
    int*    f2       = f1 + 64;
    int*    lcnt     = f2 + 64;
    ushort* Xbf      = (ushort*)(lcnt + 64 + 64);              // N*D bf16 (8 MB)
    uint32_t* Xb8    = (uint32_t*)(Xbf + (size_t)N * D);       // N*D fp8  (4 MB)

    prep_kernel<<<N + 64, 256, 0, stream>>>(X, Xbf, Xb8, sq, targets,
                                            f1, f2, lcnt, cntArr, needFB, D, N);

    dim3 grid(tiles, tiles);
    distgemm_mfma<<<grid, 256, 0, stream>>>((const uint8_t*)Xb8, sq, cand,
                                            cntArr, needFB, N, D);

    rowfinal_kernel<<<N / 4, 256, 0, stream>>>(cand, cntArr, targets, Xbf, sq,
                                               f1, f2, lcnt, needFB, rowLoss, N, D);

    fallback_kernel<<<N, 256, 0, stream>>>(Xbf, sq, targets, needFB,
                                           f1, f2, lcnt, rowLoss, N, D);

    reduce_kernel<<<1, 256, 0, stream>>>(rowLoss, out, N);
}

// Round 20
// 107.616 us; speedup vs baseline: 1.1882x; 1.0117x over previous
//
#include <hip/hip_runtime.h>
#include <hip/hip_bf16.h>
#include <cfloat>
#include <climits>
#include <cstdint>

#define ALPHA 30.0f
#define KSEL 16          // threshold = sorted[:,16] (17th smallest off-diag)
#define P0 1.368f        // candidate cutoff: E[cnt/row]≈82, P(cnt<17)~1e-13
#define P0SQ (P0 * P0)
#define CAP 224          // per-row candidate capacity (mean 82, +15 sigma)
#define TCAP 512         // per-tile candidate capacity (128² tile: mean 328, +10 sigma)
#define BIGV 1e30f
#define NMAX 4096

typedef __attribute__((ext_vector_type(4))) float f32x4;
typedef __attribute__((ext_vector_type(8))) int i32x8;
typedef __attribute__((ext_vector_type(4))) int i32x4;

#define LDS_PTR(p) ((__attribute__((address_space(3))) uint32_t*)(p))
#define GLB_PTR(p) ((const __attribute__((address_space(1))) uint32_t*)(p))

__device__ inline float bfval(ushort u) {
    return __builtin_bit_cast(float, (uint32_t)u << 16);
}

// ---------------------------------------------------------------------------
// block reduce helpers (256 threads, 4 waves)
// ---------------------------------------------------------------------------
__device__ inline float blockReduceSumF(float v, float* s) {
    for (int off = 32; off; off >>= 1) v += __shfl_down(v, off);
    int tid = threadIdx.x, wid = tid >> 6;
    if ((tid & 63) == 0) s[wid] = v;
    __syncthreads();
    float r;
    if (tid == 0) { r = s[0] + s[1] + s[2] + s[3]; s[0] = r; }
    __syncthreads();
    r = s[0];
    __syncthreads();
    return r;
}

__device__ inline int blockReduceSumI(int v, int* s) {
    for (int off = 32; off; off >>= 1) v += __shfl_down(v, off);
    int tid = threadIdx.x, wid = tid >> 6;
    if ((tid & 63) == 0) s[wid] = v;
    __syncthreads();
    int r;
    if (tid == 0) { r = s[0] + s[1] + s[2] + s[3]; s[0] = r; }
    __syncthreads();
    r = s[0];
    __syncthreads();
    return r;
}

__device__ inline int blockReduceMaxI(int v, int* s) {
    for (int off = 32; off; off >>= 1) v = max(v, __shfl_down(v, off));
    int tid = threadIdx.x, wid = tid >> 6;
    if ((tid & 63) == 0) s[wid] = v;
    __syncthreads();
    int r;
    if (tid == 0) { r = max(max(s[0], s[1]), max(s[2], s[3])); s[0] = r; }
    __syncthreads();
    r = s[0];
    __syncthreads();
    return r;
}

// ---------------------------------------------------------------------------
// Kernel 1: fused fp32 -> {bf16, fp8 e4m3 (x16)} + row sq-norm + per-row
// zeroing of cntArr/needFB; blocks >= N do labelinfo. (R19-proven)
// ---------------------------------------------------------------------------
__global__ __launch_bounds__(256) void prep_kernel(const float* __restrict__ X,
                                                   ushort* __restrict__ Xbf,
                                                   uint32_t* __restrict__ Xb8,
                                                   float* __restrict__ sq,
                                                   const int* __restrict__ targets,
                                                   int* __restrict__ f1,
                                                   int* __restrict__ f2,
                                                   int* __restrict__ lcnt,
                                                   int* __restrict__ cntArr,
                                                   int* __restrict__ needFB,
                                                   int D, int N) {
    __shared__ float sw[4];
    __shared__ int s1[4], s2[4], sc[4];
    int tid = threadIdx.x;
    int wid = tid >> 6;

    if (blockIdx.x >= (unsigned)N) {
        int lbl = blockIdx.x - N;
        int a1 = INT_MAX, a2 = INT_MAX, c = 0;
        for (int j = tid; j < N; j += 256) {
            if (targets[j] == lbl) {
                ++c;
                if (j < a1) { a2 = a1; a1 = j; }
                else if (j < a2) a2 = j;
            }
        }
        for (int off = 32; off; off >>= 1) {
            int b1 = __shfl_down(a1, off), b2 = __shfl_down(a2, off), bc = __shfl_down(c, off);
            int m1 = min(a1, b1);
            int m2 = min(max(a1, b1), min(a2, b2));
            a1 = m1; a2 = m2; c += bc;
        }
        if ((tid & 63) == 0) { s1[wid] = a1; s2[wid] = a2; sc[wid] = c; }
        __syncthreads();
        if (tid == 0) {
            int r1 = s1[0], r2 = s2[0], rc = sc[0];
            for (int w = 1; w < 4; ++w) {
                int m1 = min(r1, s1[w]);
                int m2 = min(max(r1, s1[w]), min(r2, s2[w]));
                r1 = m1; r2 = m2; rc += sc[w];
            }
            f1[lbl] = r1; f2[lbl] = r2; lcnt[lbl] = rc;
        }
        return;
    }

    int row = blockIdx.x;
    if (tid == 0) { cntArr[row] = 0; needFB[row] = 0; }
    const float4* xr = reinterpret_cast<const float4*>(X + (size_t)row * D);
    ushort4* xo = reinterpret_cast<ushort4*>(Xbf + (size_t)row * D);
    uint32_t* x8o = Xb8 + (size_t)row * (D / 4);
    float s = 0.f;
    for (int c = tid; c < D / 4; c += 256) {
        float4 v = xr[c];
        s += v.x * v.x + v.y * v.y + v.z * v.z + v.w * v.w;
        ushort4 o;
        uint32_t b;
        b = __builtin_bit_cast(uint32_t, v.x); o.x = (ushort)((b + 0x7FFF + ((b >> 16) & 1)) >> 16);
        b = __builtin_bit_cast(uint32_t, v.y); o.y = (ushort)((b + 0x7FFF + ((b >> 16) & 1)) >> 16);
        b = __builtin_bit_cast(uint32_t, v.z); o.z = (ushort)((b + 0x7FFF + ((b >> 16) & 1)) >> 16);
        b = __builtin_bit_cast(uint32_t, v.w); o.w = (ushort)((b + 0x7FFF + ((b >> 16) & 1)) >> 16);
        xo[c] = o;
        // fp8 e4m3 of 16*x (e4m3 sweet spot); GEMM epilogue divides acc by 256
        int pk = __builtin_amdgcn_cvt_pk_fp8_f32(v.x * 16.f, v.y * 16.f, 0, false);
        pk = __builtin_amdgcn_cvt_pk_fp8_f32(v.z * 16.f, v.w * 16.f, pk, true);
        x8o[c] = (uint32_t)pk;
    }
    for (int off = 32; off; off >>= 1) s += __shfl_down(s, off);
    if ((tid & 63) == 0) sw[wid] = s;
    __syncthreads();
    if (tid == 0) sq[row] = sw[0] + sw[1] + sw[2] + sw[3];
}

// ---------------------------------------------------------------------------
// Kernel 2: 128x128-tile fp8 MFMA GEMM, upper-triangle grid, TWO K-tiles per
// barrier pair: {STAGE(buf0),STAGE(buf1)} -> barrier (drains 64 loads) ->
// compute both -> barrier. Halves the per-step fixed overhead (4 drains
// instead of 8) with byte-identical STAGE/swizzle/fragment geometry (R19).
// LDS 68 KB -> 2 blocks/CU, matching the 2.06 live blocks of the triangle.
// Epilogue: ballot-compact + fused dual-push scatter (R16/R19-proven).
// ---------------------------------------------------------------------------
#define GBM 128
#define GBK 128
__global__ __launch_bounds__(256) void distgemm_mfma(const uint8_t* __restrict__ Xb8,
                                                     const float* __restrict__ sq,
                                                     float2* __restrict__ cand,
                                                     int* __restrict__ cntArr,
                                                     int* __restrict__ needFB,
                                                     int N, int D) {
    if (blockIdx.x < blockIdx.y) return;   // upper triangle only (bx >= by)
    __shared__ uint8_t As[2][GBM * GBK];   // 2 x 16 KB
    __shared__ uint8_t Bs[2][GBM * GBK];   // 2 x 16 KB
    __shared__ float2 tlist[TCAP];         // 4 KB
    __shared__ int s_cnt;

    int by = blockIdx.y, bx = blockIdx.x;
    bool diag = (bx == by);

    int tid = threadIdx.x;
    int lane = tid & 63;
    int wave = tid >> 6;       // 0..3
    int waveR = wave >> 1;     // 0..1
    int waveC = wave & 1;      // 0..1

    int rowBase = by * GBM;
    int colBase = bx * GBM;

    if (tid == 0) s_cnt = 0;

    f32x4 acc[4][4];
#pragma unroll
    for (int m = 0; m < 4; ++m)
#pragma unroll
        for (int n2 = 0; n2 < 4; ++n2) {
            f32x4 z = {0.f, 0.f, 0.f, 0.f};
            acc[m][n2] = z;
        }

    // staging: A(16KB)+B(16KB) per K-tile; 16 chunks of 1KB; wave does 4.
    // (byte-geometry identical to R16/R19 — proven)
    int srow = lane >> 3;                          // 0..7, == row&7
    int sgb = ((lane & 7) << 4) ^ (srow << 4);     // swizzled source byte in row
    auto STAGE = [&](int buf, int k0) {
#pragma unroll
        for (int p = 0; p < 4; ++p) {
            int c = wave * 4 + p;                  // 0..15
            int r = c * 8 + srow;                  // 0..127
            const uint8_t* gA = Xb8 + (size_t)(rowBase + r) * D + k0 + sgb;
            const uint8_t* gB = Xb8 + (size_t)(colBase + r) * D + k0 + sgb;
            __builtin_amdgcn_global_load_lds(GLB_PTR(gA), LDS_PTR(&As[buf][c * 1024]), 16, 0, 0);
            __builtin_amdgcn_global_load_lds(GLB_PTR(gB), LDS_PTR(&Bs[buf][c * 1024]), 16, 0, 0);
        }
    };

    int l15 = lane & 15;
    int kq32 = (lane >> 4) * 32;          // k-byte quarter base
    int rswz = (l15 & 7) << 4;            // (row&7)<<4, uniform across frags

    auto COMPUTE = [&](const uint8_t* Asb, const uint8_t* Bsb) {
        i32x8 bF[4];
#pragma unroll
        for (int n2 = 0; n2 < 4; ++n2) {
            int brl = waveC * 64 + n2 * 16 + l15;
            const uint8_t* base = Bsb + brl * 128;
            i32x4 lo = *reinterpret_cast<const i32x4*>(base + ((kq32) ^ rswz));
            i32x4 hi = *reinterpret_cast<const i32x4*>(base + ((kq32 + 16) ^ rswz));
            i32x8 f = {lo[0], lo[1], lo[2], lo[3], hi[0], hi[1], hi[2], hi[3]};
            bF[n2] = f;
        }
        __builtin_amdgcn_s_setprio(1);
#pragma unroll
        for (int m = 0; m < 4; ++m) {
            int arl = waveR * 64 + m * 16 + l15;
            const uint8_t* base = Asb + arl * 128;
            i32x4 lo = *reinterpret_cast<const i32x4*>(base + ((kq32) ^ rswz));
            i32x4 hi = *reinterpret_cast<const i32x4*>(base + ((kq32 + 16) ^ rswz));
            i32x8 aF = {lo[0], lo[1], lo[2], lo[3], hi[0], hi[1], hi[2], hi[3]};
#pragma unroll
            for (int n2 = 0; n2 < 4; ++n2)
                acc[m][n2] = __builtin_amdgcn_mfma_scale_f32_16x16x128_f8f6f4(
                    aF, bF[n2], acc[m][n2], 0, 0, 0, 0x7F, 0, 0x7F);
        }
        __builtin_amdgcn_s_setprio(0);
    };

    int npair = D / (2 * GBK);            // 4
    for (int t = 0; t < npair; ++t) {
        STAGE(0, (2 * t) * GBK);
        STAGE(1, (2 * t + 1) * GBK);
        __syncthreads();   // one drain for both buffers (64 loads in flight)
        COMPUTE(As[0], Bs[0]);
        COMPUTE(As[1], Bs[1]);
        __syncthreads();   // all waves done reading before next overwrite
    }

    // epilogue: acc = 256*dot -> v = sqi+sqj-2*dot = sqi+sqj-acc/128
    int cr = (lane >> 4) * 4;
    int cc = lane & 15;
    unsigned long long lmask_lt = (1ull << lane) - 1ull;
#pragma unroll
    for (int m = 0; m < 4; ++m) {
#pragma unroll
        for (int n2 = 0; n2 < 4; ++n2) {
            int gcol = colBase + waveC * 64 + n2 * 16 + cc;
            float sqc = sq[gcol];
#pragma unroll
            for (int r = 0; r < 4; ++r) {
                int grow = rowBase + waveR * 64 + m * 16 + cr + r;
                float v = sq[grow] + sqc - acc[m][n2][r] * 0.0078125f;  // 2/256
                bool pred = (v < P0SQ) && (grow != gcol);
                unsigned long long mask = __ballot(pred);
                if (mask) {
                    int leader = __ffsll((long long)mask) - 1;
                    int tot = __popcll(mask);
                    int base = 0;
                    if (lane == leader) base = atomicAdd(&s_cnt, tot);
                    base = __shfl(base, leader);
                    if (pred) {
                        int idx = base + __popcll(mask & lmask_lt);
                        if (idx < TCAP) {
                            float d = sqrtf(fmaxf(v, 1e-12f));
                            uint32_t pk = ((uint32_t)grow << 12) | (uint32_t)gcol;
                            float2 e; e.x = d; e.y = __builtin_bit_cast(float, pk);
                            tlist[idx] = e;
                        }
                    }
                }
            }
        }
    }
    __syncthreads();

    // fused scatter: push records straight to per-row candidate lists.
    // off-diag tiles dual-push (i,j)&(j,i); diag tiles see both orders already.
    int cnt = min(s_cnt, TCAP);
    for (int e = tid; e < cnt; e += 256) {
        float2 v = tlist[e];
        uint32_t pk = __builtin_bit_cast(uint32_t, v.y);
        int i = (int)(pk >> 12), j = (int)(pk & 4095u);
        int p = atomicAdd(&cntArr[i], 1);
        if (p < CAP) {
            float2 e1; e1.x = v.x; e1.y = __builtin_bit_cast(float, j);
            cand[(size_t)i * CAP + p] = e1;
        }
        if (!diag) {
            int q = atomicAdd(&cntArr[j], 1);
            if (q < CAP) {
                float2 e2; e2.x = v.x; e2.y = __builtin_bit_cast(float, i);
                cand[(size_t)j * CAP + q] = e2;
            }
        }
    }
    if (s_cnt > TCAP) {   // astronomically unlikely; exact fallback covers it
        if (tid < GBM) needFB[rowBase + tid] = 1;
        else needFB[colBase + tid - GBM] = 1;
    }
}

// ---------------------------------------------------------------------------
// Kernel 3: per-row finalize from candidate lists. One WAVE per row (4/block).
// (identical to R14/R16/R19 version — proven)
// ---------------------------------------------------------------------------
__global__ __launch_bounds__(256) void rowfinal_kernel(const float2* __restrict__ cand,
                                                       const int* __restrict__ cntArr,
                                                       const int* __restrict__ targets,
                                                       const ushort* __restrict__ Xbf,
                                                       const float* __restrict__ sq,
                                                       const int* __restrict__ f1,
                                                       const int* __restrict__ f2,
                                                       const int* __restrict__ lcnt,
                                                       int* __restrict__ needFB,
                                                       float* __restrict__ rowLoss,
                                                       int N, int D) {
    __shared__ float dbuf[4][CAP];
    int tid = threadIdx.x, lane = tid & 63, w = tid >> 6;
    int row = blockIdx.x * 4 + w;
    int ti = targets[row];
    int lc = lcnt[ti];
    bool validRow = (lc >= 2) && (lc < N);
    int cnt = cntArr[row];
    bool fb = (cnt < KSEL + 1) || (cnt > CAP);
    int lim = fb ? 0 : cnt;

    float ed[4]; int ej[4];
#pragma unroll
    for (int s = 0; s < 4; ++s) {
        int idx = lane + s * 64;
        bool in = (!fb) && (idx < cnt);
        if (in) {
            float2 e = cand[(size_t)row * CAP + idx];
            ed[s] = e.x; ej[s] = __builtin_bit_cast(int, e.y);
            dbuf[w][idx] = e.x;
        } else { ed[s] = BIGV; ej[s] = -1; }
    }
    __syncthreads();

    // exact rank: thr = value at rank KSEL (0-based) among candidates
    int rlo[4] = {0, 0, 0, 0}, req[4] = {0, 0, 0, 0};
    for (int q = 0; q < lim; ++q) {
        float u = dbuf[w][q];
#pragma unroll
        for (int s = 0; s < 4; ++s) {
            rlo[s] += (u < ed[s]);
            req[s] += (u == ed[s]);
        }
    }
    float thrc = BIGV;
#pragma unroll
    for (int s = 0; s < 4; ++s)
        if (ej[s] >= 0 && rlo[s] <= KSEL && KSEL < rlo[s] + req[s]) thrc = fminf(thrc, ed[s]);
    for (int off = 32; off; off >>= 1) thrc = fminf(thrc, __shfl_down(thrc, off));
    float thr = __shfl(thrc, 0);

    // masked sums over candidates (below-thr set fully contained in list)
    float posS = 0.f, negS = 0.f;
    int apb = 0;
#pragma unroll
    for (int s = 0; s < 4; ++s) {
        if (ej[s] >= 0 && ed[s] < thr) {
            bool same = (targets[ej[s]] == ti);
            float e = expf(ALPHA * (1.0f - ed[s]));
            if (same) { posS += e; apb = 1; }
            else negS += e;
        }
    }
    for (int off = 32; off; off >>= 1) {
        posS += __shfl_down(posS, off);
        negS += __shfl_down(negS, off);
        apb = max(apb, __shfl_down(apb, off));
    }

    // first-positive fallback distance (bf16 dot, fp32 accum)
    int fp = 0;
    float dot = 0.f;
    if (validRow) {
        fp = (row == f1[ti]) ? f2[ti] : f1[ti];
        const ushort* xr = Xbf + (size_t)row * D;
        const ushort* xf = Xbf + (size_t)fp * D;
        for (int c = lane; c < D / 4; c += 64) {
            ushort4 a = *reinterpret_cast<const ushort4*>(xr + (size_t)c * 4);
            ushort4 b = *reinterpret_cast<const ushort4*>(xf + (size_t)c * 4);
            dot += bfval(a.x) * bfval(b.x) + bfval(a.y) * bfval(b.y)
                 + bfval(a.z) * bfval(b.z) + bfval(a.w) * bfval(b.w);
        }
    }
    for (int off = 32; off; off >>= 1) dot += __shfl_down(dot, off);

    if (lane == 0) {
        if (fb) {
            needFB[row] = 1;
        } else if (!validRow) {
            rowLoss[row] = BIGV;
        } else {
            float fbD = sqrtf(fmaxf(sq[row] + sq[fp] - 2.0f * dot, 1e-12f));
            float posLogit = apb ? posS : expf(ALPHA * (1.0f - fbD));
            rowLoss[row] = -logf(posLogit / (posLogit + negS));
        }
    }
}

// ---------------------------------------------------------------------------
// Kernel 4: exact fallback (full-row recompute, bf16). Expected zero work.
// (identical to R14/R16/R19 version — proven)
// ---------------------------------------------------------------------------
__global__ __launch_bounds__(256) void fallback_kernel(const ushort* __restrict__ Xbf,
                                                       const float* __restrict__ sq,
                                                       const int* __restrict__ targets,
                                                       const int* __restrict__ needFB,
                                                       const int* __restrict__ f1,
                                                       const int* __restrict__ f2,
                                                       const int* __restrict__ lcnt,
                                                       float* __restrict__ rowLoss,
                                                       int N, int D) {
    int row = blockIdx.x;
    if (!needFB[row]) return;

    __shared__ float xrow[1024];
    __shared__ float rowD[NMAX];
    __shared__ float sF[4];
    __shared__ int sI[4];
    int tid = threadIdx.x;

    for (int k = tid; k < D; k += 256) xrow[k] = bfval(Xbf[(size_t)row * D + k]);
    __syncthreads();

    for (int j = tid; j < N; j += 256) {
        float dot = 0.f;
        const ushort* xj = Xbf + (size_t)j * D;
        for (int k = 0; k < D; ++k) dot += xrow[k] * bfval(xj[k]);
        rowD[j] = (j == row) ? BIGV
                             : sqrtf(fmaxf(sq[row] + sq[j] - 2.0f * dot, 1e-12f));
    }
    __syncthreads();

    uint32_t lo = 0, hi = 0x40800000u;
    while (lo < hi) {
        uint32_t mid = (lo + hi) >> 1;
        float mv = __builtin_bit_cast(float, mid);
        int c = 0;
        for (int j = tid; j < N; j += 256) c += (rowD[j] <= mv);
        c = blockReduceSumI(c, sI);
        if (c >= KSEL + 1) hi = mid; else lo = mid + 1;
    }
    float thr = __builtin_bit_cast(float, hi);

    int ti = targets[row];
    int lc = lcnt[ti];
    bool validRow = (lc >= 2) && (lc < N);

    float posS = 0.f, negS = 0.f;
    int apb = 0;
    for (int j = tid; j < N; j += 256) {
        if (j == row) continue;
        float d = rowD[j];
        bool same = (targets[j] == ti);
        if (d < thr) {
            float e = expf(ALPHA * (1.0f - d));
            if (same) { posS += e; apb = 1; }
            else negS += e;
        }
    }
    posS = blockReduceSumF(posS, sF);
    negS = blockReduceSumF(negS, sF);
    apb = blockReduceMaxI(apb, sI);

    if (tid == 0) {
        if (!validRow) { rowLoss[row] = BIGV; return; }
        int fp = (row == f1[ti]) ? f2[ti] : f1[ti];
        float posLogit = apb ? posS : expf(ALPHA * (1.0f - rowD[fp]));
        rowLoss[row] = -logf(posLogit / (posLogit + negS));
    }
}

// ---------------------------------------------------------------------------
// Kernel 5: single-block reduction over rowLoss -> out[4]
// ---------------------------------------------------------------------------
__global__ __launch_bounds__(256) void reduce_kernel(const float* __restrict__ rowLoss,
                                                     float* __restrict__ out, int N) {
    __shared__ float sF[4];
    __shared__ int sI[4];
    int tid = threadIdx.x;
    float sumL = 0.f;
    int nValid = 0, nAcc = 0;
    for (int j = tid; j < N; j += 256) {
        float L = rowLoss[j];
        if (L != BIGV) {
            sumL += L;
            ++nValid;
            if (L < 0.6f) ++nAcc;
        }
    }
    sumL = blockReduceSumF(sumL, sF);
    nValid = blockReduceSumI(nValid, sI);
    nAcc = blockReduceSumI(nAcc, sI);
    if (tid == 0) {
        out[0] = (nValid > 0) ? sumL / (float)nValid : 0.f;
        out[1] = (float)nAcc / (float)N;
        out[2] = 0.f;
        out[3] = 0.f;
    }
}

// ---------------------------------------------------------------------------
extern "C" void kernel_launch(void* const* d_in, const int* in_sizes, int n_in,
                              void* d_out, int out_size, void* d_ws, size_t ws_size,
                              hipStream_t stream) {
    const float* X = (const float*)d_in[0];
    const int* targets = (const int*)d_in[1];
    float* out = (float*)d_out;

    int N = in_sizes[1];             // 4096
    int D = in_sizes[0] / N;         // 1024
    int tiles = N / GBM;             // 32

    // 8B-aligned float2 array first
    float2* cand     = (float2*)d_ws;                          // N*CAP f2 (7.3 MB)
    float*  sq       = (float*)(cand + (size_t)N * CAP);
    float*  rowLoss  = sq + N;
    int*    cntArr   = (int*)(rowLoss + N);
    int*    needFB   = cntArr + N;
    int*    f1       = needFB + N;
    int*    f2       = f1 + 64;
    int*    lcnt     = f2 + 64;
    ushort* Xbf      = (ushort*)(lcnt + 64 + 64);              // N*D bf16 (8 MB)
    uint32_t* Xb8    = (uint32_t*)(Xbf + (size_t)N * D);       // N*D fp8  (4 MB)

    prep_kernel<<<N + 64, 256, 0, stream>>>(X, Xbf, Xb8, sq, targets,
                                            f1, f2, lcnt, cntArr, needFB, D, N);

    dim3 grid(tiles, tiles);
    distgemm_mfma<<<grid, 256, 0, stream>>>((const uint8_t*)Xb8, sq, cand,
                                            cntArr, needFB, N, D);

    rowfinal_kernel<<<N / 4, 256, 0, stream>>>(cand, cntArr, targets, Xbf, sq,
                                               f1, f2, lcnt, needFB, rowLoss, N, D);

    fallback_kernel<<<N, 256, 0, stream>>>(Xbf, sq, targets, needFB,
                                           f1, f2, lcnt, rowLoss, N, D);

    reduce_kernel<<<1, 256, 0, stream>>>(rowLoss, out, N);
}